// Round 10
// baseline (39.894 us; speedup 1.0000x reference)
//
#include <hip/hip_runtime.h>
#include <math.h>

#define Bn 8
#define Cc 512
#define Nn 4096   // 64*64
#define Mm 1024   // 32*32 pooled
#define C8 64
#define C2 256

typedef float f4 __attribute__((ext_vector_type(4)));   // nontemporal builtins need ext_vector

// K1: xm[b,c] = mean_n x[b,c,n], 2 rows per block; then (gamma!=0) grid-stride q/kp/vp tails.
__global__ void meanqkv_kernel(const float* __restrict__ x, float* __restrict__ xm,
                               const float* __restrict__ wq, const float* __restrict__ bq,
                               const float* __restrict__ wk, const float* __restrict__ bk,
                               const float* __restrict__ wv, const float* __restrict__ bv,
                               const float* __restrict__ gamma,
                               float* __restrict__ q, float* __restrict__ kp,
                               float* __restrict__ vp) {
    int bc2 = blockIdx.x;                      // 0..2047 (2 rows each)
    int t = threadIdx.x;                       // 256
    const f4* r0 = (const f4*)(x + (size_t)(bc2 * 2) * Nn);
    const f4* r1 = (const f4*)(x + (size_t)(bc2 * 2 + 1) * Nn);
    f4 v0[4], v1[4];
    #pragma unroll
    for (int i = 0; i < 4; i++) v0[i] = __builtin_nontemporal_load(r0 + t + i * 256);
    #pragma unroll
    for (int i = 0; i < 4; i++) v1[i] = __builtin_nontemporal_load(r1 + t + i * 256);
    float s0 = 0.f, s1 = 0.f;
    #pragma unroll
    for (int i = 0; i < 4; i++) {
        s0 += v0[i].x + v0[i].y + v0[i].z + v0[i].w;
        s1 += v1[i].x + v1[i].y + v1[i].z + v1[i].w;
    }
    __shared__ float red[2][4];
    for (int off = 32; off; off >>= 1) {
        s0 += __shfl_down(s0, off);
        s1 += __shfl_down(s1, off);
    }
    if ((t & 63) == 0) { red[0][t >> 6] = s0; red[1][t >> 6] = s1; }
    __syncthreads();
    if (t == 0) xm[bc2 * 2]     = (red[0][0] + red[0][1] + red[0][2] + red[0][3]) * (1.f / Nn);
    if (t == 1) xm[bc2 * 2 + 1] = (red[1][0] + red[1][1] + red[1][2] + red[1][3]) * (1.f / Nn);

    if (gamma[0] == 0.f) return;               // uniform

    // ---- gamma != 0: produce q, kp, vp (grid-stride; correctness path) ----
    const size_t TOT = (size_t)2048 * 256;
    size_t tid = (size_t)bc2 * 256 + t;

    for (size_t idx = tid; idx < (size_t)Bn * C8 * Nn; idx += TOT) {
        int n = idx & (Nn - 1); size_t rest = idx >> 12;
        int o = rest & (C8 - 1); int b = rest >> 6;
        const float* xb = x + (size_t)b * Cc * Nn + n;
        const float* wr = wq + (size_t)o * Cc;
        float acc = 0.f;
        for (int c = 0; c < Cc; c++) acc += wr[c] * xb[(size_t)c * Nn];
        q[idx] = acc + bq[o];
    }
    for (size_t idx = tid; idx < (size_t)Bn * C8 * Mm; idx += TOT) {
        int m = idx & (Mm - 1); size_t rest = idx >> 10;
        int o = rest & (C8 - 1); int b = rest >> 6;
        int n0 = (m >> 5) * 128 + (m & 31) * 2;
        const float* xb = x + (size_t)b * Cc * Nn;
        const float* wr = wk + (size_t)o * Cc;
        float a0 = 0, a1 = 0, a2 = 0, a3 = 0;
        for (int c = 0; c < Cc; c++) {
            const float* xc = xb + (size_t)c * Nn + n0;
            float wv_ = wr[c];
            a0 += wv_ * xc[0]; a1 += wv_ * xc[1];
            a2 += wv_ * xc[64]; a3 += wv_ * xc[65];
        }
        kp[idx] = fmaxf(fmaxf(a0, a1), fmaxf(a2, a3)) + bk[o];
    }
    for (size_t idx = tid; idx < (size_t)Bn * C2 * Mm; idx += TOT) {
        int m = idx & (Mm - 1); size_t rest = idx >> 10;
        int o = rest & (C2 - 1); int b = rest >> 8;
        int n0 = (m >> 5) * 128 + (m & 31) * 2;
        const float* xb = x + (size_t)b * Cc * Nn;
        const float* wr = wv + (size_t)o * Cc;
        float a0 = 0, a1 = 0, a2 = 0, a3 = 0;
        for (int c = 0; c < Cc; c++) {
            const float* xc = xb + (size_t)c * Nn + n0;
            float wv_ = wr[c];
            a0 += wv_ * xc[0]; a1 += wv_ * xc[1];
            a2 += wv_ * xc[64]; a3 += wv_ * xc[65];
        }
        vp[idx] = fmaxf(fmaxf(a0, a1), fmaxf(a2, a3)) + bv[o];
    }
}

// K2: se1 (always; wave (bid*4+w) computes h[b,j], 512 blocks) then
//     gamma-guarded per-(b,n) softmax-attention, grid-stride over 32768 rows.
__global__ void attn_se1_kernel(const float* __restrict__ q, const float* __restrict__ kp,
                                const float* __restrict__ vp, float* __restrict__ ao,
                                const float* __restrict__ gamma,
                                const float* __restrict__ xm, const float* __restrict__ fc1,
                                float* __restrict__ hbuf) {
    int t = threadIdx.x, bid = blockIdx.x;
    // ---- se1: h[b,j] = relu(xm[b,:] . fc1[j,:]); 2048 waves across 512 blocks ----
    {
        int w = t >> 6, ln = t & 63;
        int p = bid * 4 + w;                   // p = b*C2 + j, p < 2048
        int b = p >> 8, j = p & 255;
        const float* w1 = fc1 + (size_t)j * Cc;
        const float* xb = xm + b * Cc;
        float a = 0.f;
        #pragma unroll
        for (int k = 0; k < Cc / 64; k++) a += xb[ln + k * 64] * w1[ln + k * 64];
        for (int off = 32; off; off >>= 1) a += __shfl_down(a, off);
        if (ln == 0) hbuf[p] = fmaxf(a, 0.f);
    }

    if (gamma[0] == 0.f) return;               // uniform, before any sync

    __shared__ float qs[C8];
    __shared__ float ps[Mm];
    __shared__ float red[4];
    for (int it = bid; it < Nn * Bn; it += gridDim.x) {
        int n = it & (Nn - 1), b = it >> 12;
        if (t < C8) qs[t] = q[((size_t)(b * C8 + t)) * Nn + n];
        __syncthreads();
        float e[4];
        for (int j = 0; j < 4; j++) {
            int m = t + j * 256;
            float a = 0.f;
            for (int c = 0; c < C8; c++) a += qs[c] * kp[((size_t)(b * C8 + c)) * Mm + m];
            e[j] = a;
        }
        float mx = fmaxf(fmaxf(e[0], e[1]), fmaxf(e[2], e[3]));
        for (int off = 32; off; off >>= 1) mx = fmaxf(mx, __shfl_down(mx, off));
        if ((t & 63) == 0) red[t >> 6] = mx;
        __syncthreads();
        mx = fmaxf(fmaxf(red[0], red[1]), fmaxf(red[2], red[3]));
        float s = 0.f;
        for (int j = 0; j < 4; j++) {
            float p = expf(e[j] - mx);
            ps[t + j * 256] = p;
            s += p;
        }
        for (int off = 32; off; off >>= 1) s += __shfl_down(s, off);
        __syncthreads();
        if ((t & 63) == 0) red[t >> 6] = s;
        __syncthreads();
        float inv = 1.f / (red[0] + red[1] + red[2] + red[3]);
        float a = 0.f;
        const float* vrow = vp + ((size_t)(b * C2 + t)) * Mm;
        for (int mm = 0; mm < Mm; mm++) a += vrow[mm] * ps[mm];
        ao[((size_t)(b * C2 + t)) * Nn + n] = a * inv;
        __syncthreads();
    }
}

// K3: two output channels per block (o, o+256). Fused se2 reduces for both, then
//     out = gamma*(wo @ ao + bo) + x*y. grid (256, Bn), 256 thr.
__global__ void final_kernel(const float* __restrict__ x, const float* __restrict__ ao,
                             const float* __restrict__ wo, const float* __restrict__ bo,
                             const float* __restrict__ hbuf, const float* __restrict__ fc2,
                             const float* __restrict__ gamma, float* __restrict__ out) {
    int t = threadIdx.x;
    int o1 = blockIdx.x, o2 = o1 + 256, b = blockIdx.y;
    size_t base1 = ((size_t)(b * Cc + o1)) * Nn;
    size_t base2 = ((size_t)(b * Cc + o2)) * Nn;
    const f4* xr1 = (const f4*)(x + base1);
    const f4* xr2 = (const f4*)(x + base2);
    f4* ow1 = (f4*)(out + base1);
    f4* ow2 = (f4*)(out + base2);

    // issue x loads first (in flight during the reduces)
    f4 xv1[4], xv2[4];
    #pragma unroll
    for (int i = 0; i < 4; i++) xv1[i] = __builtin_nontemporal_load(xr1 + t + i * 256);
    #pragma unroll
    for (int i = 0; i < 4; i++) xv2[i] = __builtin_nontemporal_load(xr2 + t + i * 256);

    // fused se2 for both channels: j == t (C2 == 256 == blockDim)
    float hv = hbuf[b * C2 + t];
    float p1 = hv * fc2[(size_t)o1 * C2 + t];
    float p2 = hv * fc2[(size_t)o2 * C2 + t];
    __shared__ float red[2][4];
    for (int off = 32; off; off >>= 1) {
        p1 += __shfl_down(p1, off);
        p2 += __shfl_down(p2, off);
    }
    if ((t & 63) == 0) { red[0][t >> 6] = p1; red[1][t >> 6] = p2; }
    __syncthreads();
    float yb1 = 1.f / (1.f + expf(-(red[0][0] + red[0][1] + red[0][2] + red[0][3])));
    float yb2 = 1.f / (1.f + expf(-(red[1][0] + red[1][1] + red[1][2] + red[1][3])));

    float g = gamma[0];
    if (g == 0.f) {
        #pragma unroll
        for (int i = 0; i < 4; i++) {
            f4 r1 = xv1[i] * yb1;
            __builtin_nontemporal_store(r1, ow1 + t + i * 256);
        }
        #pragma unroll
        for (int i = 0; i < 4; i++) {
            f4 r2 = xv2[i] * yb2;
            __builtin_nontemporal_store(r2, ow2 + t + i * 256);
        }
    } else {
        #pragma unroll
        for (int half = 0; half < 2; half++) {
            int o = half ? o2 : o1;
            float yb = half ? yb2 : yb1;
            f4* orw = half ? ow2 : ow1;
            f4* xv = half ? xv2 : xv1;
            const float* wrow = wo + (size_t)o * C2;
            float bb = bo[o];
            #pragma unroll
            for (int i = 0; i < 4; i++) {
                int n4 = t + i * 256;
                int n = n4 * 4;
                float a0 = 0, a1 = 0, a2 = 0, a3 = 0;
                for (int c2 = 0; c2 < C2; c2++) {
                    const float* arow = ao + ((size_t)(b * C2 + c2)) * Nn + n;
                    float wv_ = wrow[c2];
                    a0 += wv_ * arow[0]; a1 += wv_ * arow[1];
                    a2 += wv_ * arow[2]; a3 += wv_ * arow[3];
                }
                f4 r;
                r.x = xv[i].x * yb + g * (a0 + bb);
                r.y = xv[i].y * yb + g * (a1 + bb);
                r.z = xv[i].z * yb + g * (a2 + bb);
                r.w = xv[i].w * yb + g * (a3 + bb);
                orw[n4] = r;
            }
        }
    }
}

// ---------------- launch ----------------

extern "C" void kernel_launch(void* const* d_in, const int* in_sizes, int n_in,
                              void* d_out, int out_size, void* d_ws, size_t ws_size,
                              hipStream_t stream) {
    const float* x   = (const float*)d_in[0];
    const float* wq  = (const float*)d_in[1];
    const float* bq  = (const float*)d_in[2];
    const float* wk  = (const float*)d_in[3];
    const float* bk  = (const float*)d_in[4];
    const float* wv  = (const float*)d_in[5];
    const float* bv  = (const float*)d_in[6];
    const float* wo  = (const float*)d_in[7];
    const float* bo  = (const float*)d_in[8];
    const float* fc1 = (const float*)d_in[9];
    const float* fc2 = (const float*)d_in[10];
    const float* gm  = (const float*)d_in[11];
    float* out = (float*)d_out;
    float* ws  = (float*)d_ws;

    float* xm = ws;                        // B*C
    float* hb = xm + Bn * Cc;              // B*C2
    float* q  = hb + Bn * C2;              // B*C8*N
    float* kp = q  + (size_t)Bn * C8 * Nn; // B*C8*M
    float* vp = kp + (size_t)Bn * C8 * Mm; // B*C2*M
    float* ao = vp + (size_t)Bn * C2 * Mm; // B*C2*N

    meanqkv_kernel<<<dim3(Bn * Cc / 2), dim3(256), 0, stream>>>(x, xm, wq, bq, wk, bk, wv, bv,
                                                                gm, q, kp, vp);
    attn_se1_kernel<<<dim3(512), dim3(256), 0, stream>>>(q, kp, vp, ao, gm, xm, fc1, hb);
    final_kernel<<<dim3(C2, Bn), dim3(256), 0, stream>>>(x, ao, wo, bo, hb, fc2, gm, out);
}

// Round 11
// 36.563 us; speedup vs baseline: 1.0911x; 1.0911x over previous
//
#include <hip/hip_runtime.h>
#include <math.h>

#define Bn 8
#define Cc 512
#define Nn 4096   // 64*64
#define Mm 1024   // 32*32 pooled
#define C8 64
#define C2 256

typedef float f4 __attribute__((ext_vector_type(4)));   // nontemporal builtins need ext_vector

// K1: xm[b,c] = mean_n x[b,c,n]; then (gamma!=0) grid-stride tails produce q, kp, vp.
__global__ void meanqkv_kernel(const float* __restrict__ x, float* __restrict__ xm,
                               const float* __restrict__ wq, const float* __restrict__ bq,
                               const float* __restrict__ wk, const float* __restrict__ bk,
                               const float* __restrict__ wv, const float* __restrict__ bv,
                               const float* __restrict__ gamma,
                               float* __restrict__ q, float* __restrict__ kp,
                               float* __restrict__ vp) {
    int bc = blockIdx.x;                       // 0..B*C-1 (4096 blocks)
    int t = threadIdx.x;                       // 256
    const f4* r4 = (const f4*)(x + (size_t)bc * Nn);
    float s = 0.f;
    #pragma unroll
    for (int i = 0; i < 4; i++) {
        f4 v = __builtin_nontemporal_load(r4 + t + i * 256);
        s += v.x + v.y + v.z + v.w;
    }
    __shared__ float red[4];
    for (int off = 32; off; off >>= 1) s += __shfl_down(s, off);
    if ((t & 63) == 0) red[t >> 6] = s;
    __syncthreads();
    if (t == 0) xm[bc] = (red[0] + red[1] + red[2] + red[3]) * (1.f / Nn);

    if (gamma[0] == 0.f) return;               // uniform

    // ---- gamma != 0: produce q, kp, vp (grid-stride; correctness path) ----
    const size_t TOT = (size_t)4096 * 256;
    size_t tid = (size_t)bc * 256 + t;

    for (size_t idx = tid; idx < (size_t)Bn * C8 * Nn; idx += TOT) {
        int n = idx & (Nn - 1); size_t rest = idx >> 12;
        int o = rest & (C8 - 1); int b = rest >> 6;
        const float* xb = x + (size_t)b * Cc * Nn + n;
        const float* wr = wq + (size_t)o * Cc;
        float acc = 0.f;
        for (int c = 0; c < Cc; c++) acc += wr[c] * xb[(size_t)c * Nn];
        q[idx] = acc + bq[o];
    }
    for (size_t idx = tid; idx < (size_t)Bn * C8 * Mm; idx += TOT) {
        int m = idx & (Mm - 1); size_t rest = idx >> 10;
        int o = rest & (C8 - 1); int b = rest >> 6;
        int n0 = (m >> 5) * 128 + (m & 31) * 2;
        const float* xb = x + (size_t)b * Cc * Nn;
        const float* wr = wk + (size_t)o * Cc;
        float a0 = 0, a1 = 0, a2 = 0, a3 = 0;
        for (int c = 0; c < Cc; c++) {
            const float* xc = xb + (size_t)c * Nn + n0;
            float wv_ = wr[c];
            a0 += wv_ * xc[0]; a1 += wv_ * xc[1];
            a2 += wv_ * xc[64]; a3 += wv_ * xc[65];
        }
        kp[idx] = fmaxf(fmaxf(a0, a1), fmaxf(a2, a3)) + bk[o];
    }
    for (size_t idx = tid; idx < (size_t)Bn * C2 * Mm; idx += TOT) {
        int m = idx & (Mm - 1); size_t rest = idx >> 10;
        int o = rest & (C2 - 1); int b = rest >> 8;
        int n0 = (m >> 5) * 128 + (m & 31) * 2;
        const float* xb = x + (size_t)b * Cc * Nn;
        const float* wr = wv + (size_t)o * Cc;
        float a0 = 0, a1 = 0, a2 = 0, a3 = 0;
        for (int c = 0; c < Cc; c++) {
            const float* xc = xb + (size_t)c * Nn + n0;
            float wv_ = wr[c];
            a0 += wv_ * xc[0]; a1 += wv_ * xc[1];
            a2 += wv_ * xc[64]; a3 += wv_ * xc[65];
        }
        vp[idx] = fmaxf(fmaxf(a0, a1), fmaxf(a2, a3)) + bv[o];
    }
}

// K2: se1 (always; wave (bid*4+w) computes h[b,j], 512 blocks) then
//     gamma-guarded per-(b,n) softmax-attention, grid-stride over 32768 rows.
__global__ void attn_se1_kernel(const float* __restrict__ q, const float* __restrict__ kp,
                                const float* __restrict__ vp, float* __restrict__ ao,
                                const float* __restrict__ gamma,
                                const float* __restrict__ xm, const float* __restrict__ fc1,
                                float* __restrict__ hbuf) {
    int t = threadIdx.x, bid = blockIdx.x;
    // ---- se1: h[b,j] = relu(xm[b,:] . fc1[j,:]); 2048 waves across 512 blocks ----
    {
        int w = t >> 6, ln = t & 63;
        int p = bid * 4 + w;                   // p = b*C2 + j, p < 2048
        int b = p >> 8, j = p & 255;
        const float* w1 = fc1 + (size_t)j * Cc;
        const float* xb = xm + b * Cc;
        float a = 0.f;
        #pragma unroll
        for (int k = 0; k < Cc / 64; k++) a += xb[ln + k * 64] * w1[ln + k * 64];
        for (int off = 32; off; off >>= 1) a += __shfl_down(a, off);
        if (ln == 0) hbuf[p] = fmaxf(a, 0.f);
    }

    if (gamma[0] == 0.f) return;               // uniform, before any sync

    __shared__ float qs[C8];
    __shared__ float ps[Mm];
    __shared__ float red[4];
    for (int it = bid; it < Nn * Bn; it += gridDim.x) {
        int n = it & (Nn - 1), b = it >> 12;
        if (t < C8) qs[t] = q[((size_t)(b * C8 + t)) * Nn + n];
        __syncthreads();
        float e[4];
        for (int j = 0; j < 4; j++) {
            int m = t + j * 256;
            float a = 0.f;
            for (int c = 0; c < C8; c++) a += qs[c] * kp[((size_t)(b * C8 + c)) * Mm + m];
            e[j] = a;
        }
        float mx = fmaxf(fmaxf(e[0], e[1]), fmaxf(e[2], e[3]));
        for (int off = 32; off; off >>= 1) mx = fmaxf(mx, __shfl_down(mx, off));
        if ((t & 63) == 0) red[t >> 6] = mx;
        __syncthreads();
        mx = fmaxf(fmaxf(red[0], red[1]), fmaxf(red[2], red[3]));
        float s = 0.f;
        for (int j = 0; j < 4; j++) {
            float p = expf(e[j] - mx);
            ps[t + j * 256] = p;
            s += p;
        }
        for (int off = 32; off; off >>= 1) s += __shfl_down(s, off);
        __syncthreads();
        if ((t & 63) == 0) red[t >> 6] = s;
        __syncthreads();
        float inv = 1.f / (red[0] + red[1] + red[2] + red[3]);
        float a = 0.f;
        const float* vrow = vp + ((size_t)(b * C2 + t)) * Mm;
        for (int mm = 0; mm < Mm; mm++) a += vrow[mm] * ps[mm];
        ao[((size_t)(b * C2 + t)) * Nn + n] = a * inv;
        __syncthreads();
    }
}

// K3: y[b,o] = sigmoid(hb[b,:].fc2[o,:]) (in-block reduce, x loads hoisted above),
//     then out = gamma*(wo @ ao + bo) + x*y. grid (Cc, Bn), 256 thr, 4 float4/thread.
__global__ void final_kernel(const float* __restrict__ x, const float* __restrict__ ao,
                             const float* __restrict__ wo, const float* __restrict__ bo,
                             const float* __restrict__ hbuf, const float* __restrict__ fc2,
                             const float* __restrict__ gamma, float* __restrict__ out) {
    int t = threadIdx.x;
    int o = blockIdx.x, b = blockIdx.y;
    size_t base = ((size_t)(b * Cc + o)) * Nn;
    const f4* xr = (const f4*)(x + base);
    f4* orw = (f4*)(out + base);

    // issue x loads first (in flight during the reduce)
    f4 xv[4];
    #pragma unroll
    for (int i = 0; i < 4; i++) xv[i] = __builtin_nontemporal_load(xr + t + i * 256);

    // fused se2: j == t (C2 == 256 == blockDim)
    float part = hbuf[b * C2 + t] * fc2[(size_t)o * C2 + t];
    __shared__ float red[4];
    for (int off = 32; off; off >>= 1) part += __shfl_down(part, off);
    if ((t & 63) == 0) red[t >> 6] = part;
    __syncthreads();
    float yb = 1.f / (1.f + expf(-(red[0] + red[1] + red[2] + red[3])));

    float g = gamma[0];
    if (g == 0.f) {
        #pragma unroll
        for (int i = 0; i < 4; i++) {
            f4 r = xv[i] * yb;
            __builtin_nontemporal_store(r, orw + t + i * 256);
        }
    } else {
        const float* wrow = wo + (size_t)o * C2;
        float bb = bo[o];
        #pragma unroll
        for (int i = 0; i < 4; i++) {
            int n4 = t + i * 256;
            int n = n4 * 4;
            float a0 = 0, a1 = 0, a2 = 0, a3 = 0;
            for (int c2 = 0; c2 < C2; c2++) {
                const float* arow = ao + ((size_t)(b * C2 + c2)) * Nn + n;
                float wv_ = wrow[c2];
                a0 += wv_ * arow[0]; a1 += wv_ * arow[1];
                a2 += wv_ * arow[2]; a3 += wv_ * arow[3];
            }
            f4 r;
            r.x = xv[i].x * yb + g * (a0 + bb);
            r.y = xv[i].y * yb + g * (a1 + bb);
            r.z = xv[i].z * yb + g * (a2 + bb);
            r.w = xv[i].w * yb + g * (a3 + bb);
            orw[n4] = r;
        }
    }
}

// ---------------- launch ----------------

extern "C" void kernel_launch(void* const* d_in, const int* in_sizes, int n_in,
                              void* d_out, int out_size, void* d_ws, size_t ws_size,
                              hipStream_t stream) {
    const float* x   = (const float*)d_in[0];
    const float* wq  = (const float*)d_in[1];
    const float* bq  = (const float*)d_in[2];
    const float* wk  = (const float*)d_in[3];
    const float* bk  = (const float*)d_in[4];
    const float* wv  = (const float*)d_in[5];
    const float* bv  = (const float*)d_in[6];
    const float* wo  = (const float*)d_in[7];
    const float* bo  = (const float*)d_in[8];
    const float* fc1 = (const float*)d_in[9];
    const float* fc2 = (const float*)d_in[10];
    const float* gm  = (const float*)d_in[11];
    float* out = (float*)d_out;
    float* ws  = (float*)d_ws;

    float* xm = ws;                        // B*C
    float* hb = xm + Bn * Cc;              // B*C2
    float* q  = hb + Bn * C2;              // B*C8*N
    float* kp = q  + (size_t)Bn * C8 * Nn; // B*C8*M
    float* vp = kp + (size_t)Bn * C8 * Mm; // B*C2*M
    float* ao = vp + (size_t)Bn * C2 * Mm; // B*C2*N

    meanqkv_kernel<<<dim3(Bn * Cc), dim3(256), 0, stream>>>(x, xm, wq, bq, wk, bk, wv, bv,
                                                            gm, q, kp, vp);
    attn_se1_kernel<<<dim3(512), dim3(256), 0, stream>>>(q, kp, vp, ao, gm, xm, fc1, hb);
    final_kernel<<<dim3(Cc, Bn), dim3(256), 0, stream>>>(x, ao, wo, bo, hb, fc2, gm, out);
}